// Round 19
// baseline (92.294 us; speedup 1.0000x reference)
//
#include <hip/hip_runtime.h>

#define NEARV    0.2f
#define LOWPASSV 0.3f

constexpr int HH = 80, WW = 80;
constexpr int CFE = 32;          // feature channels
constexpr int NZ = 6;            // z-levels per (x,y) cell (grid 32x32x6)

constexpr int NCELL = 1024;      // N / NZ
constexpr int HMAX = NCELL * NZ; // 6144 header slots per camera

typedef unsigned long long u64;
typedef unsigned int u32;
typedef float v2f __attribute__((ext_vector_type(2)));

// ------- Kernel S: FUSED rank + projection, wide shape (R17/R18 verbatim, passed) -------
// 96 blocks on 96 CUs: stage all 1024 keys (4KB LDS) -> rank 64 owned cells
// (4 threads/cell, quarter-range counts, shfl-combined) -> project 384
// gaussians straight into rank slots. Keys (HW-verified R7-R18, absmax
// bit-identical): depth -> monotone 26-bit -> 22-bit; packed=(key22<<10)|cell
// UNIQUE -> rank == stable argsort position. Projection: baked log2e
// constants hdrA=(u,v,A2,B2), hdrB=(C2,op,r2,gi). KEY ALGEBRA (verified):
// scales SCALAR per gaussian => cov = s^2 * J*J^T.
__global__ __launch_bounds__(256) void prep_kernel(
    const float* __restrict__ pc_xyz, const float* __restrict__ cam_rot,
    const float* __restrict__ cam_trans, const float* __restrict__ cam_intr,
    const float* __restrict__ density, const float* __restrict__ scales,
    int N, int NC,
    int* __restrict__ counts, float4* __restrict__ hdrA,
    float4* __restrict__ hdrB)
{
  __shared__ u32 sk[NCELL];              // 4 KB
  __shared__ int rnk[64];                // owned cells' global ranks
  __shared__ u32 wred[4];

  const int cam = blockIdx.y;
  const int tid = threadIdx.x;           // 0..255
  const float* R = cam_rot + cam*9;
  const float* t = cam_trans + cam*3;
  const float R20 = R[6], R21 = R[7], R22 = R[8];
  const float t2  = t[2];

  int vcnt = 0;
  #pragma unroll
  for (int e4 = 0; e4 < NCELL/256; ++e4) {
    const int cell = e4*256 + tid;
    const int i0 = cell * NZ;
    u32 key22 = 0x3FFFFFu;               // invalid marker: sorts last
    if (i0 < N) {
      float c2 = R20*pc_xyz[i0*3+0] + R21*pc_xyz[i0*3+1] + R22*pc_xyz[i0*3+2] + t2;
      if (c2 > NEARV) {
        u32 b = __float_as_uint(c2) - 0x3E000000u;   // monotone, 26 bits
        b = b < 0x03FFFF00u ? b : 0x03FFFF00u;       // clamp below marker
        key22 = b >> 4;                              // 22 bits, < 0x3FFFFF
        ++vcnt;
      }
    }
    sk[cell] = (key22 << 10) | (u32)cell;
  }
  __syncthreads();

  const int cbase = blockIdx.x * 64;
  const int cl = tid >> 2;               // local cell 0..63
  const int q  = tid & 3;                // quarter 0..3
  const u32 mykey = sk[cbase + cl];
  const uint4* k4 = (const uint4*)sk;
  int r = 0;
  #pragma unroll 8
  for (int i = 0; i < 64; ++i) {         // 64 uint4 = 256 keys
    const uint4 kv = k4[q*64 + i];
    r += (int)(kv.x < mykey) + (int)(kv.y < mykey)
       + (int)(kv.z < mykey) + (int)(kv.w < mykey);
  }
  r += __shfl_xor(r, 1, 64);
  r += __shfl_xor(r, 2, 64);
  if (q == 0) rnk[cl] = r;

  if (blockIdx.x == 0) {
    #pragma unroll
    for (int off = 32; off > 0; off >>= 1) vcnt += __shfl_down(vcnt, off, 64);
    if ((tid & 63) == 0) wred[tid >> 6] = (u32)vcnt;
  }
  __syncthreads();                       // rnk + wred visible
  if (blockIdx.x == 0 && tid == 0)
    counts[cam] = (int)(wred[0] + wred[1] + wred[2] + wred[3]) * NZ;

  const float* intr = cam_intr + cam*4;
  const float fx = intr[0], fy = intr[1], cx = intr[2], cy = intr[3];
  const float R0=R[0],R1=R[1],R2=R[2],R3=R[3],R4=R[4],R5=R[5];
  const float t0=t[0],t1=t[1];
  const int b = cam / NC;
  float4* hA = hdrA + (size_t)cam * HMAX;
  float4* hB = hdrB + (size_t)cam * HMAX;

  for (int g = tid; g < 64*NZ; g += 256) {
    const int cl2 = g / NZ, iz = g - cl2*NZ;
    const int n  = (cbase + cl2) * NZ + iz;   // original gaussian index
    const int kq = rnk[cl2] * NZ + iz;        // sorted header slot
    if (n >= N) continue;

    const float p0 = pc_xyz[n*3+0], p1 = pc_xyz[n*3+1], p2 = pc_xyz[n*3+2];
    const float c0 = R0*p0 + R1*p1 + R2*p2 + t0;
    const float c1 = R3*p0 + R4*p1 + R5*p2 + t1;
    const float c2 = R20*p0 + R21*p1 + R22*p2 + t2;
    const float tz = fmaxf(c2, 1e-6f);
    const float itz = 1.0f / tz;
    const float u = fx*c0*itz + cx;
    const float v = fy*c1*itz + cy;
    const float j00 = fx*itz, j02 = -(fx*c0*itz)*itz;
    const float j11 = fy*itz, j12 = -(fy*c1*itz)*itz;
    const float s = expf(scales[n]);
    const float s2 = s*s;
    const float cov00 = s2*(j00*j00 + j02*j02);
    const float cov01 = s2*(j02*j12);
    const float cov11 = s2*(j11*j11 + j12*j12);
    const float a = cov00 + LOWPASSV, bb = cov01, cc = cov11 + LOWPASSV;
    const float det = a*cc - bb*bb;
    const float idet = 1.0f / det;
    const float mid = 0.5f*(a + cc);
    const float dd = sqrtf(fmaxf(mid*mid - det, 0.f));
    float r2 = 32.f * (mid + dd);
    const float dens = density[(size_t)b*N + n];
    const float op = fmaxf(dens, 0.f) + log1pf(expf(-fabsf(dens)));  // softplus
    const float sx = fminf(fmaxf(u, 0.f), (float)(WW-1)) - u;
    const float sy = fminf(fmaxf(v, 0.f), (float)(HH-1)) - v;
    if (sx*sx + sy*sy > r2) r2 = -1.0f;

    const float L = 1.4426950408889634f;   // log2(e)
    const float A2 = -0.5f * (cc*idet) * L;
    const float C2 = -0.5f * (a*idet)  * L;
    const float B2 =         (bb*idet) * L;

    hA[kq] = make_float4(u, v, A2, B2);
    hB[kq] = make_float4(C2, op, r2, __int_as_float(n));
  }
}

// ---------- Kernel B: 2-wave depth split + saturation-abort (R19) ----------
// R18 post-mortem: wall = SILHOUETTE tiles (background px never saturate ->
// no early exit -> full K~800-1500 scan). For those, depth-split is FREE
// (no exit to lose -- R3's poison doesn't apply); for saturating tiles,
// wave0 sets sflag on saturation and wave1 ABORTS: its discarded C1 is
// scaled by T0<1e-3 in the combine -- the SAME truncation bound as the
// existing exit (R5: bound doesn't move absmax). Combine out = C0 + T0*C1
// (R3 HW-verified bit-stable). 128-thr block = wave0 [0,half) + wave1
// [half,count); per-wave LDS slabs; 3 block barriers, all outside loops.
// Everything else R18-verbatim: exact rect-max cull at the av=0 clamp
// threshold, readlane alpha, pk-FMA accumulate, ping-pong prefetch,
// wave_barrier-only chunk loop.
__global__ __launch_bounds__(128) void render_kernel(
    const float* __restrict__ vox,
    const float4* __restrict__ hdrA, const float4* __restrict__ hdrB,
    const int* __restrict__ counts,
    float* __restrict__ out, int N, int NC)
{
  __shared__ int    cgi[2][64];         // per-wave survivor index slab
  __shared__ float4 sfeat[2][64];       // per-wave feature slab (2 KB)
  __shared__ v2f    segC[64][CFE/2 + 1];// wave1 contribution, padded (8.5 KB)
  __shared__ int    sflag;              // wave0-saturated flag

  const int cam = blockIdx.y;
  const int tile = blockIdx.x;          // 5 x 20 tiles of 16x4 px
  const int tx = tile % (WW/16), ty = tile / (WW/16);
  const int tidb = threadIdx.x;
  const int wv = tidb >> 6;             // 0 = front segment, 1 = back
  const int lane = tidb & 63;
  const int lx = lane & 15, ly = lane >> 4;
  const int px = tx*16 + lx, py = ty*4 + ly;
  const float fpx = (float)px, fpy = (float)py;
  const float tx0 = (float)(tx*16), tx1 = tx0 + 15.f;
  const float ty0 = (float)(ty*4),  ty1 = ty0 + 3.f;
  const int count = counts[cam];
  const int b = cam / NC;
  const float4* hA = hdrA + (size_t)cam * HMAX;
  const float4* hB = hdrB + (size_t)cam * HMAX;
  const float4* voxb = (const float4*)vox + (size_t)b * N * (CFE/4);

  // chunk-aligned depth split
  int half = ((count/2 + 63) >> 6) << 6;
  if (half > count) half = count;
  const int kb = wv ? half : 0;
  const int ke = wv ? count : half;

  if (tidb == 0) sflag = 0;
  __syncthreads();

  int* cgw = cgi[wv];
  float4* sfw = sfeat[wv];

  v2f acc2[CFE/2];                      // 16 packed pairs = 32 channels
  #pragma unroll
  for (int i = 0; i < CFE/2; ++i) { acc2[i].x = 0.f; acc2[i].y = 0.f; }
  float T = 1.0f;
  bool done = false;

#define RDLN(x, l) __uint_as_float(__builtin_amdgcn_readlane(__float_as_uint(x), (l)))

#define LOAD4(Aarr, Barr, base_) do {                                   \
    _Pragma("unroll")                                                   \
    for (int d_ = 0; d_ < 4; ++d_) {                                    \
      const int kn_ = min((base_) + d_*64 + lane, ke - 1);              \
      Aarr[d_] = hA[kn_]; Barr[d_] = hB[kn_];                           \
    } } while (0)

#define PROCESS_CHUNK(k0_, a0_, b0_) do {                               \
    const int ki = (k0_) + lane;                                        \
    /* exact rect-max of concave pl2 = A2 dx^2 + C2 dy^2 + B2 dxdy */   \
    const float gu = (a0_).x, gv = (a0_).y;                             \
    const float gA = (a0_).z, gB = (a0_).w, gC = (b0_).x;               \
    const float dxl = tx0 - gu, dxh = tx1 - gu;                         \
    const float dyl = ty0 - gv, dyh = ty1 - gv;                         \
    const float X = fmaxf(dxl, fminf(0.f, dxh));                        \
    const float Y = fmaxf(dyl, fminf(0.f, dyh));                        \
    const float dyv = fmaxf(dyl, fminf((gB*X) / (-2.0f*gC), dyh));      \
    const float P1 = gA*X*X + gC*dyv*dyv + gB*X*dyv;                    \
    const float dxv = fmaxf(dxl, fminf((gB*Y) / (-2.0f*gA), dxh));      \
    const float P2 = gA*dxv*dxv + gC*Y*Y + gB*dxv*Y;                    \
    const bool hit = (ki < ke) && (fmaxf(P1, P2) > -23.0831f);          \
    const u64 m = __ballot(hit);                                        \
    const int P = __popcll(m);                                          \
    if (P == 0) continue;                                               \
    if (hit) {                                                          \
      const int pos = (int)__popcll(m & ((1ull << lane) - 1ull));       \
      cgw[pos] = __float_as_int((b0_).w);                               \
    }                                                                   \
    __builtin_amdgcn_wave_barrier();  /* keep DS order: compact < reads */ \
    const int sl = lane >> 3, sc = lane & 7;                            \
    float4 pf = voxb[(size_t)cgw[min(sl, P - 1)] * (CFE/4) + sc];       \
    u64 mm_ = m;                      /* uniform survivor-lane stream */ \
    for (int j = 0; j < P; j += 8) {                                    \
      float al[8];                                                      \
      _Pragma("unroll")                                                 \
      for (int qq = 0; qq < 8; ++qq) {                                  \
        const int idx = j + qq;                                         \
        int lq = 0;                                                     \
        if (mm_) { lq = (int)__builtin_ctzll(mm_); mm_ &= mm_ - 1; }    \
        const float su  = RDLN((a0_).x, lq);                            \
        const float sv  = RDLN((a0_).y, lq);                            \
        const float sA2 = RDLN((a0_).z, lq);                            \
        const float sB2 = RDLN((a0_).w, lq);                            \
        const float sC2 = RDLN((b0_).x, lq);                            \
        const float sop = RDLN((b0_).y, lq);                            \
        const float dx = fpx - su, dy = fpy - sv;                       \
        const float pl2 = sA2*(dx*dx) + sC2*(dy*dy) + sB2*(dx*dy);      \
        float av = fminf(sop * __builtin_exp2f(fminf(pl2, 0.f)), 0.99f); \
        av = (pl2 > -23.0831f) ? av : 0.f;  /* 2^-23.08 = 1.1e-7 */     \
        al[qq] = (idx < P) ? av : 0.f;                                  \
      }                                                                 \
      sfw[lane] = pf;                   /* publish group j */           \
      if (j + 8 < P) {                  /* gather next group */          \
        const int si = min(j + 8 + sl, P - 1);                          \
        pf = voxb[(size_t)cgw[si] * (CFE/4) + sc];                      \
      }                                                                 \
      __builtin_amdgcn_wave_barrier(); /* publish < composite reads */  \
      _Pragma("unroll")                                                 \
      for (int qq = 0; qq < 8; ++qq) {                                  \
        const float w = T * al[qq];                                     \
        T -= w;                                                         \
        if (__any(w > 1e-8f)) {                                         \
          const float4* fj = &sfw[qq * 8];                              \
          v2f w2; w2.x = w; w2.y = w;                                   \
          _Pragma("unroll")                                             \
          for (int c8 = 0; c8 < CFE/4; ++c8) {                          \
            const float4 fv = fj[c8];                                   \
            v2f lo; lo.x = fv.x; lo.y = fv.y;                           \
            v2f hi; hi.x = fv.z; hi.y = fv.w;                           \
            asm("v_pk_fma_f32 %0, %1, %2, %0"                           \
                : "+v"(acc2[c8*2+0]) : "v"(w2), "v"(lo));               \
            asm("v_pk_fma_f32 %0, %1, %2, %0"                           \
                : "+v"(acc2[c8*2+1]) : "v"(w2), "v"(hi));               \
          }                                                             \
        }                                                               \
      }                                                                 \
      if (__all(T < 1e-3f)) { done = true; break; }                     \
      __builtin_amdgcn_wave_barrier(); /* reads < next publish (WAR) */ \
    }                                                                   \
  } while (0)

  if (ke > kb) {
    float4 A0x[4], B0x[4], A1x[4], B1x[4];
    const int nquad = (ke - kb + 255) >> 8;   // groups of 4 chunks
    LOAD4(A0x, B0x, kb);

    for (int q = 0; q < nquad && !done; q += 2) {
      if (q + 1 < nquad) LOAD4(A1x, B1x, kb + (q+1)*256);
      #pragma unroll
      for (int d = 0; d < 4; ++d) {
        if (done) break;
        if (wv && *(volatile int*)&sflag) { done = true; break; }  // abort
        const int k0 = kb + q*256 + d*64;
        if (k0 >= ke) break;
        PROCESS_CHUNK(k0, A0x[d], B0x[d]);
      }
      if (done || q + 1 >= nquad) break;
      if (q + 2 < nquad) LOAD4(A0x, B0x, kb + (q+2)*256);
      #pragma unroll
      for (int d = 0; d < 4; ++d) {
        if (done) break;
        if (wv && *(volatile int*)&sflag) { done = true; break; }  // abort
        const int k0 = kb + (q+1)*256 + d*64;
        if (k0 >= ke) break;
        PROCESS_CHUNK(k0, A1x[d], B1x[d]);
      }
    }
  }
#undef PROCESS_CHUNK
#undef LOAD4
#undef RDLN

  // wave0 saturated: signal wave1 to abort (its C1 is scaled by T0<1e-3)
  if (wv == 0 && done) *(volatile int*)&sflag = 1;

  // ---- combine: out = C0 + T0*C1 (R3 HW-verified factorization) ----
  __syncthreads();
  if (wv == 1) {
    #pragma unroll
    for (int c8 = 0; c8 < CFE/2; ++c8) segC[lane][c8] = acc2[c8];
  }
  __syncthreads();
  if (wv == 0) {
    v2f t2v; t2v.x = T; t2v.y = T;
    #pragma unroll
    for (int c8 = 0; c8 < CFE/2; ++c8) {
      const v2f c1 = segC[lane][c8];
      acc2[c8].x = fmaf(t2v.x, c1.x, acc2[c8].x);
      acc2[c8].y = fmaf(t2v.y, c1.y, acc2[c8].y);
    }
    float* ob = out + (((size_t)cam * CFE) * HH + py) * WW + px;
    #pragma unroll
    for (int c8 = 0; c8 < CFE/2; ++c8) {
      ob[(size_t)(2*c8+0) * HH * WW] = acc2[c8].x;
      ob[(size_t)(2*c8+1) * HH * WW] = acc2[c8].y;
    }
  }
}

extern "C" void kernel_launch(void* const* d_in, const int* in_sizes, int n_in,
                              void* d_out, int out_size, void* d_ws, size_t ws_size,
                              hipStream_t stream) {
  const float* vox       = (const float*)d_in[0];
  const float* density   = (const float*)d_in[1];
  const float* cam_rot   = (const float*)d_in[2];
  const float* cam_trans = (const float*)d_in[3];
  const float* cam_intr  = (const float*)d_in[4];
  const float* pc_xyz    = (const float*)d_in[5];
  const float* scales    = (const float*)d_in[6];
  float* out = (float*)d_out;

  const int N    = in_sizes[5] / 3;       // 6144
  const int NCAM = in_sizes[4] / 4;       // B*NC = 6
  const int B    = in_sizes[1] / N;       // 1
  const int NC   = NCAM / B;              // 6

  unsigned char* ws = (unsigned char*)d_ws;
  int* countsPtr = (int*)ws;                                   // 256 B
  float4* hdrA   = (float4*)(ws + 32768);                      // 590 KB
  float4* hdrB   = (float4*)(ws + 32768 + (size_t)NCAM * HMAX * sizeof(float4));

  prep_kernel<<<dim3(NCELL/64, NCAM), 256, 0, stream>>>(
      pc_xyz, cam_rot, cam_trans, cam_intr, density, scales, N, NC,
      countsPtr, hdrA, hdrB);
  render_kernel<<<dim3((WW/16)*(HH/4), NCAM), 128, 0, stream>>>(
      vox, hdrA, hdrB, countsPtr, out, N, NC);
}

// Round 20
// 79.763 us; speedup vs baseline: 1.1571x; 1.1571x over previous
//
#include <hip/hip_runtime.h>

#define NEARV    0.2f
#define LOWPASSV 0.3f

constexpr int HH = 80, WW = 80;
constexpr int CFE = 32;          // feature channels
constexpr int NZ = 6;            // z-levels per (x,y) cell (grid 32x32x6)

constexpr int NCELL = 1024;      // N / NZ
constexpr int HMAX = NCELL * NZ; // 6144 header slots per camera

typedef unsigned long long u64;
typedef unsigned int u32;
typedef float v2f __attribute__((ext_vector_type(2)));

// ------- Kernel S: FUSED rank + projection, wide shape (R17/R18 verbatim, passed) -------
// 96 blocks on 96 CUs: stage all 1024 keys (4KB LDS) -> rank 64 owned cells
// (4 threads/cell, quarter-range counts, shfl-combined) -> project 384
// gaussians straight into rank slots. Keys (HW-verified R7-R18, absmax
// bit-identical): depth -> monotone 26-bit -> 22-bit; packed=(key22<<10)|cell
// UNIQUE -> rank == stable argsort position. Projection: baked log2e
// constants hdrA=(u,v,A2,B2), hdrB=(C2,op,r2,gi). KEY ALGEBRA (verified):
// scales SCALAR per gaussian => cov = s^2 * J*J^T.
__global__ __launch_bounds__(256) void prep_kernel(
    const float* __restrict__ pc_xyz, const float* __restrict__ cam_rot,
    const float* __restrict__ cam_trans, const float* __restrict__ cam_intr,
    const float* __restrict__ density, const float* __restrict__ scales,
    int N, int NC,
    int* __restrict__ counts, float4* __restrict__ hdrA,
    float4* __restrict__ hdrB)
{
  __shared__ u32 sk[NCELL];              // 4 KB
  __shared__ int rnk[64];                // owned cells' global ranks
  __shared__ u32 wred[4];

  const int cam = blockIdx.y;
  const int tid = threadIdx.x;           // 0..255
  const float* R = cam_rot + cam*9;
  const float* t = cam_trans + cam*3;
  const float R20 = R[6], R21 = R[7], R22 = R[8];
  const float t2  = t[2];

  int vcnt = 0;
  #pragma unroll
  for (int e4 = 0; e4 < NCELL/256; ++e4) {
    const int cell = e4*256 + tid;
    const int i0 = cell * NZ;
    u32 key22 = 0x3FFFFFu;               // invalid marker: sorts last
    if (i0 < N) {
      float c2 = R20*pc_xyz[i0*3+0] + R21*pc_xyz[i0*3+1] + R22*pc_xyz[i0*3+2] + t2;
      if (c2 > NEARV) {
        u32 b = __float_as_uint(c2) - 0x3E000000u;   // monotone, 26 bits
        b = b < 0x03FFFF00u ? b : 0x03FFFF00u;       // clamp below marker
        key22 = b >> 4;                              // 22 bits, < 0x3FFFFF
        ++vcnt;
      }
    }
    sk[cell] = (key22 << 10) | (u32)cell;
  }
  __syncthreads();

  const int cbase = blockIdx.x * 64;
  const int cl = tid >> 2;               // local cell 0..63
  const int q  = tid & 3;                // quarter 0..3
  const u32 mykey = sk[cbase + cl];
  const uint4* k4 = (const uint4*)sk;
  int r = 0;
  #pragma unroll 8
  for (int i = 0; i < 64; ++i) {         // 64 uint4 = 256 keys
    const uint4 kv = k4[q*64 + i];
    r += (int)(kv.x < mykey) + (int)(kv.y < mykey)
       + (int)(kv.z < mykey) + (int)(kv.w < mykey);
  }
  r += __shfl_xor(r, 1, 64);
  r += __shfl_xor(r, 2, 64);
  if (q == 0) rnk[cl] = r;

  if (blockIdx.x == 0) {
    #pragma unroll
    for (int off = 32; off > 0; off >>= 1) vcnt += __shfl_down(vcnt, off, 64);
    if ((tid & 63) == 0) wred[tid >> 6] = (u32)vcnt;
  }
  __syncthreads();                       // rnk + wred visible
  if (blockIdx.x == 0 && tid == 0)
    counts[cam] = (int)(wred[0] + wred[1] + wred[2] + wred[3]) * NZ;

  const float* intr = cam_intr + cam*4;
  const float fx = intr[0], fy = intr[1], cx = intr[2], cy = intr[3];
  const float R0=R[0],R1=R[1],R2=R[2],R3=R[3],R4=R[4],R5=R[5];
  const float t0=t[0],t1=t[1];
  const int b = cam / NC;
  float4* hA = hdrA + (size_t)cam * HMAX;
  float4* hB = hdrB + (size_t)cam * HMAX;

  for (int g = tid; g < 64*NZ; g += 256) {
    const int cl2 = g / NZ, iz = g - cl2*NZ;
    const int n  = (cbase + cl2) * NZ + iz;   // original gaussian index
    const int kq = rnk[cl2] * NZ + iz;        // sorted header slot
    if (n >= N) continue;

    const float p0 = pc_xyz[n*3+0], p1 = pc_xyz[n*3+1], p2 = pc_xyz[n*3+2];
    const float c0 = R0*p0 + R1*p1 + R2*p2 + t0;
    const float c1 = R3*p0 + R4*p1 + R5*p2 + t1;
    const float c2 = R20*p0 + R21*p1 + R22*p2 + t2;
    const float tz = fmaxf(c2, 1e-6f);
    const float itz = 1.0f / tz;
    const float u = fx*c0*itz + cx;
    const float v = fy*c1*itz + cy;
    const float j00 = fx*itz, j02 = -(fx*c0*itz)*itz;
    const float j11 = fy*itz, j12 = -(fy*c1*itz)*itz;
    const float s = expf(scales[n]);
    const float s2 = s*s;
    const float cov00 = s2*(j00*j00 + j02*j02);
    const float cov01 = s2*(j02*j12);
    const float cov11 = s2*(j11*j11 + j12*j12);
    const float a = cov00 + LOWPASSV, bb = cov01, cc = cov11 + LOWPASSV;
    const float det = a*cc - bb*bb;
    const float idet = 1.0f / det;
    const float mid = 0.5f*(a + cc);
    const float dd = sqrtf(fmaxf(mid*mid - det, 0.f));
    float r2 = 32.f * (mid + dd);
    const float dens = density[(size_t)b*N + n];
    const float op = fmaxf(dens, 0.f) + log1pf(expf(-fabsf(dens)));  // softplus
    const float sx = fminf(fmaxf(u, 0.f), (float)(WW-1)) - u;
    const float sy = fminf(fmaxf(v, 0.f), (float)(HH-1)) - v;
    if (sx*sx + sy*sy > r2) r2 = -1.0f;

    const float L = 1.4426950408889634f;   // log2(e)
    const float A2 = -0.5f * (cc*idet) * L;
    const float C2 = -0.5f * (a*idet)  * L;
    const float B2 =         (bb*idet) * L;

    hA[kq] = make_float4(u, v, A2, B2);
    hB[kq] = make_float4(C2, op, r2, __int_as_float(n));
  }
}

// ---------- Kernel B: EXACT-tile-cull compositing + PACKED-FMA accumulate (R18 verbatim, 79.6us best) ----------
// R19 post-mortem: depth-split regressed AGAIN (+12.7) -- wave1's parallel
// back-half scan is pure added work on saturating tiles (sflag arrives only
// at wave0 exit) and doubles per-CU issue pressure. Conclusion (R3+R19):
// depth parallelism always adds more work than it removes here; the
// front-to-back prefix with early exit is near the minimal composite set.
// This kernel is the measured best: single wave per 16x4 tile, exact
// rect-max cull at the av=0 clamp threshold (bit-identical), readlane
// alpha (no LDS on alpha path), v_pk_fma_f32 packed accumulate
// (bit-identical IEEE fma per component), ping-pong header prefetch,
// no __syncthreads (single-wave DS ordering, HW-verified R13-R18).
__global__ __launch_bounds__(64) void render_kernel(
    const float* __restrict__ vox,
    const float4* __restrict__ hdrA, const float4* __restrict__ hdrB,
    const int* __restrict__ counts,
    float* __restrict__ out, int N, int NC)
{
  __shared__ int   cgi[64];             // compacted survivor original index
  __shared__ float4 sfeat[64];          // current 8 survivors' features (1 KB)

  const int cam = blockIdx.y;
  const int tile = blockIdx.x;          // 5 x 20 tiles of 16x4 px
  const int tx = tile % (WW/16), ty = tile / (WW/16);
  const int lane = threadIdx.x;
  const int lx = lane & 15, ly = lane >> 4;
  const int px = tx*16 + lx, py = ty*4 + ly;
  const float fpx = (float)px, fpy = (float)py;
  const float tx0 = (float)(tx*16), tx1 = tx0 + 15.f;
  const float ty0 = (float)(ty*4),  ty1 = ty0 + 3.f;
  const int count = counts[cam];
  const int b = cam / NC;
  const float4* hA = hdrA + (size_t)cam * HMAX;
  const float4* hB = hdrB + (size_t)cam * HMAX;
  const float4* voxb = (const float4*)vox + (size_t)b * N * (CFE/4);

  v2f acc2[CFE/2];                      // 16 packed pairs = 32 channels
  #pragma unroll
  for (int i = 0; i < CFE/2; ++i) { acc2[i].x = 0.f; acc2[i].y = 0.f; }
  float T = 1.0f;
  bool done = false;

#define RDLN(x, l) __uint_as_float(__builtin_amdgcn_readlane(__float_as_uint(x), (l)))

#define LOAD4(Aarr, Barr, base_) do {                                   \
    _Pragma("unroll")                                                   \
    for (int d_ = 0; d_ < 4; ++d_) {                                    \
      const int kn_ = min((base_) + d_*64 + lane, count - 1);           \
      Aarr[d_] = hA[kn_]; Barr[d_] = hB[kn_];                           \
    } } while (0)

#define PROCESS_CHUNK(k0_, a0_, b0_) do {                               \
    const int ki = (k0_) + lane;                                        \
    /* exact rect-max of concave pl2 = A2 dx^2 + C2 dy^2 + B2 dxdy */   \
    const float gu = (a0_).x, gv = (a0_).y;                             \
    const float gA = (a0_).z, gB = (a0_).w, gC = (b0_).x;               \
    const float dxl = tx0 - gu, dxh = tx1 - gu;                         \
    const float dyl = ty0 - gv, dyh = ty1 - gv;                         \
    const float X = fmaxf(dxl, fminf(0.f, dxh));                        \
    const float Y = fmaxf(dyl, fminf(0.f, dyh));                        \
    const float dyv = fmaxf(dyl, fminf((gB*X) / (-2.0f*gC), dyh));      \
    const float P1 = gA*X*X + gC*dyv*dyv + gB*X*dyv;                    \
    const float dxv = fmaxf(dxl, fminf((gB*Y) / (-2.0f*gA), dxh));      \
    const float P2 = gA*dxv*dxv + gC*Y*Y + gB*dxv*Y;                    \
    const bool hit = (ki < count) && (fmaxf(P1, P2) > -23.0831f);       \
    const u64 m = __ballot(hit);                                        \
    const int P = __popcll(m);                                          \
    if (P == 0) continue;                                               \
    if (hit) {                                                          \
      const int pos = (int)__popcll(m & ((1ull << lane) - 1ull));       \
      cgi[pos] = __float_as_int((b0_).w);                               \
    }                                                                   \
    __builtin_amdgcn_wave_barrier();  /* keep DS order: compact < reads */ \
    const int sl = lane >> 3, sc = lane & 7;                            \
    float4 pf = voxb[(size_t)cgi[min(sl, P - 1)] * (CFE/4) + sc];       \
    u64 mm_ = m;                      /* uniform survivor-lane stream */ \
    for (int j = 0; j < P; j += 8) {                                    \
      float al[8];                                                      \
      _Pragma("unroll")                                                 \
      for (int qq = 0; qq < 8; ++qq) {                                  \
        const int idx = j + qq;                                         \
        int lq = 0;                                                     \
        if (mm_) { lq = (int)__builtin_ctzll(mm_); mm_ &= mm_ - 1; }    \
        const float su  = RDLN((a0_).x, lq);                            \
        const float sv  = RDLN((a0_).y, lq);                            \
        const float sA2 = RDLN((a0_).z, lq);                            \
        const float sB2 = RDLN((a0_).w, lq);                            \
        const float sC2 = RDLN((b0_).x, lq);                            \
        const float sop = RDLN((b0_).y, lq);                            \
        const float dx = fpx - su, dy = fpy - sv;                       \
        const float pl2 = sA2*(dx*dx) + sC2*(dy*dy) + sB2*(dx*dy);      \
        float av = fminf(sop * __builtin_exp2f(fminf(pl2, 0.f)), 0.99f); \
        av = (pl2 > -23.0831f) ? av : 0.f;  /* 2^-23.08 = 1.1e-7 */     \
        al[qq] = (idx < P) ? av : 0.f;                                  \
      }                                                                 \
      sfeat[lane] = pf;                 /* publish group j */           \
      if (j + 8 < P) {                  /* gather next group */          \
        const int si = min(j + 8 + sl, P - 1);                          \
        pf = voxb[(size_t)cgi[si] * (CFE/4) + sc];                      \
      }                                                                 \
      __builtin_amdgcn_wave_barrier(); /* publish < composite reads */  \
      _Pragma("unroll")                                                 \
      for (int qq = 0; qq < 8; ++qq) {                                  \
        const float w = T * al[qq];                                     \
        T -= w;                                                         \
        if (__any(w > 1e-8f)) {                                         \
          const float4* fj = &sfeat[qq * 8];                            \
          v2f w2; w2.x = w; w2.y = w;                                   \
          _Pragma("unroll")                                             \
          for (int c8 = 0; c8 < CFE/4; ++c8) {                          \
            const float4 fv = fj[c8];                                   \
            v2f lo; lo.x = fv.x; lo.y = fv.y;                           \
            v2f hi; hi.x = fv.z; hi.y = fv.w;                           \
            asm("v_pk_fma_f32 %0, %1, %2, %0"                           \
                : "+v"(acc2[c8*2+0]) : "v"(w2), "v"(lo));               \
            asm("v_pk_fma_f32 %0, %1, %2, %0"                           \
                : "+v"(acc2[c8*2+1]) : "v"(w2), "v"(hi));               \
          }                                                             \
        }                                                               \
      }                                                                 \
      if (__all(T < 1e-3f)) { done = true; break; }                     \
      __builtin_amdgcn_wave_barrier(); /* reads < next publish (WAR) */ \
    }                                                                   \
  } while (0)

  if (count > 0) {
    float4 A0x[4], B0x[4], A1x[4], B1x[4];
    const int nquad = (count + 255) >> 8;   // groups of 4 chunks
    LOAD4(A0x, B0x, 0);

    for (int q = 0; q < nquad && !done; q += 2) {
      if (q + 1 < nquad) LOAD4(A1x, B1x, (q+1)*256);
      #pragma unroll
      for (int d = 0; d < 4; ++d) {
        if (done) break;
        const int k0 = q*256 + d*64;
        if (k0 >= count) break;
        PROCESS_CHUNK(k0, A0x[d], B0x[d]);
      }
      if (done || q + 1 >= nquad) break;
      if (q + 2 < nquad) LOAD4(A0x, B0x, (q+2)*256);
      #pragma unroll
      for (int d = 0; d < 4; ++d) {
        if (done) break;
        const int k0 = (q+1)*256 + d*64;
        if (k0 >= count) break;
        PROCESS_CHUNK(k0, A1x[d], B1x[d]);
      }
    }
  }
#undef PROCESS_CHUNK
#undef LOAD4
#undef RDLN

  // write this lane's pixel: all 32 channels (compile-time vector indices)
  float* ob = out + (((size_t)cam * CFE) * HH + py) * WW + px;
  #pragma unroll
  for (int c8 = 0; c8 < CFE/2; ++c8) {
    ob[(size_t)(2*c8+0) * HH * WW] = acc2[c8].x;
    ob[(size_t)(2*c8+1) * HH * WW] = acc2[c8].y;
  }
}

extern "C" void kernel_launch(void* const* d_in, const int* in_sizes, int n_in,
                              void* d_out, int out_size, void* d_ws, size_t ws_size,
                              hipStream_t stream) {
  const float* vox       = (const float*)d_in[0];
  const float* density   = (const float*)d_in[1];
  const float* cam_rot   = (const float*)d_in[2];
  const float* cam_trans = (const float*)d_in[3];
  const float* cam_intr  = (const float*)d_in[4];
  const float* pc_xyz    = (const float*)d_in[5];
  const float* scales    = (const float*)d_in[6];
  float* out = (float*)d_out;

  const int N    = in_sizes[5] / 3;       // 6144
  const int NCAM = in_sizes[4] / 4;       // B*NC = 6
  const int B    = in_sizes[1] / N;       // 1
  const int NC   = NCAM / B;              // 6

  unsigned char* ws = (unsigned char*)d_ws;
  int* countsPtr = (int*)ws;                                   // 256 B
  float4* hdrA   = (float4*)(ws + 32768);                      // 590 KB
  float4* hdrB   = (float4*)(ws + 32768 + (size_t)NCAM * HMAX * sizeof(float4));

  prep_kernel<<<dim3(NCELL/64, NCAM), 256, 0, stream>>>(
      pc_xyz, cam_rot, cam_trans, cam_intr, density, scales, N, NC,
      countsPtr, hdrA, hdrB);
  render_kernel<<<dim3((WW/16)*(HH/4), NCAM), 64, 0, stream>>>(
      vox, hdrA, hdrB, countsPtr, out, N, NC);
}